// Round 3
// baseline (768.531 us; speedup 1.0000x reference)
//
#include <hip/hip_runtime.h>
#include <stdint.h>

typedef unsigned long long u64;
typedef unsigned short u16;

// ---------------- sizes ----------------
// x: [4096,12,12,15]  conv1(pad1)->[B,48,12,15]  pool->[B,48,11,14]
// conv2(pad0)->[B,48,9,12]  conv3(pad0)->[B,48,7,10]  pool->[B,48,6,9]
// fc: [B,2592] @ [5,2592]^T

#define NB 4096

// ---------------- workspace layout (bytes) ----------------
// stats: long long, idx = stat*8 + slot; stat: c, 48+c, 96+c, 144+c, 192+c, 240+c
#define WS_STATS 0          // 2304*8 = 18432 B
#define WS_W1P   20480      // u16[432]
#define WS_W2P   24576      // u64[432]
#define WS_W3P   28672      // u64[432]
#define WS_WFCP  32768      // u64[205]
#define WS_A1    40960      // u16[4096*180]; reused as A2 u64[4096*154]
#define WS_P1    5111808    // pooled1 s8[4096*7392]; reused as pooled3 s16[4096*2592]

// ---------------- d_out offsets (floats) ----------------
#define OUT_OFF 0
#define XB1_OFF 20480
#define XB2_OFF 8867840
#define XB3_OFF 39145472
#define FB_OFF  60379136

__device__ __forceinline__ float fsign(float v) {
    return (v > 0.0f) ? 1.0f : ((v < 0.0f) ? -1.0f : 0.0f);
}

// ---- weight binarize+pack, stats zero ----
__global__ __launch_bounds__(512)
void kw_pack(const float* __restrict__ w1, const float* __restrict__ w2,
             const float* __restrict__ w3, const float* __restrict__ wfc,
             char* __restrict__ ws) {
    int t = threadIdx.x;
    long long* stats = (long long*)(ws + WS_STATS);
    for (int i = t; i < 2304; i += 512) stats[i] = 0;
    if (t < 432) {
        int oc = t / 9, p = t % 9;
        u16 m1 = 0;
        for (int c = 0; c < 12; ++c)
            if (w1[oc*108 + c*9 + p] > 0.0f) m1 |= (u16)(1u << c);
        ((u16*)(ws + WS_W1P))[t] = m1;
        u64 m2 = 0, m3 = 0;
        for (int c = 0; c < 48; ++c) {
            if (w2[oc*432 + c*9 + p] > 0.0f) m2 |= (1ull << c);
            if (w3[oc*432 + c*9 + p] > 0.0f) m3 |= (1ull << c);
        }
        ((u64*)(ws + WS_W2P))[t] = m2;
        ((u64*)(ws + WS_W3P))[t] = m3;
    }
    if (t < 205) {
        int o = t / 41, j = t % 41;
        u64 m = 0;
        for (int l = 0; l < 64; ++l) {
            int k = j*64 + l;
            if (k < 2592 && wfc[o*2592 + k] > 0.0f) m |= (1ull << l);
        }
        ((u64*)(ws + WS_WFCP))[t] = m;
    }
}

// ---- binarize x -> xb1 floats (float4) + A1 bitmasks ----
__global__ __launch_bounds__(256)
void k0_binx(const float* __restrict__ x, float* __restrict__ dout,
             char* __restrict__ ws) {
    int id = blockIdx.x*256 + threadIdx.x;   // 184320 = 4096*45
    int b = id / 45, s4 = id % 45;
    const float4* xp = (const float4*)(x + b*2160);
    float4* op = (float4*)(dout + XB1_OFF + (size_t)b*2160);
    u16 m0 = 0, m1 = 0, m2 = 0, m3 = 0;
    #pragma unroll
    for (int c = 0; c < 12; ++c) {
        float4 v = xp[c*45 + s4];
        float4 o;
        o.x = fsign(v.x); o.y = fsign(v.y); o.z = fsign(v.z); o.w = fsign(v.w);
        op[c*45 + s4] = o;
        u16 bit = (u16)(1u << c);
        if (v.x > 0.0f) m0 |= bit;
        if (v.y > 0.0f) m1 |= bit;
        if (v.z > 0.0f) m2 |= bit;
        if (v.w > 0.0f) m3 |= bit;
    }
    ushort4 mm; mm.x = m0; mm.y = m1; mm.z = m2; mm.w = m3;
    *((ushort4*)((u16*)(ws + WS_A1) + b*180 + s4*4)) = mm;
}

// ---- conv1 (pad1, taps-in-regs, scalar weights) + pool + BN1 stats ----
__global__ __launch_bounds__(192)
void k1_conv1(char* __restrict__ ws) {
    __shared__ u16 As[180];
    __shared__ signed char cmap[8640];   // [48][180]
    __shared__ signed char pl[7392];     // [48][154]
    int t = threadIdx.x, b = blockIdx.x;
    const u16* A1 = (const u16*)(ws + WS_A1) + b*180;
    if (t < 180) As[t] = A1[t];
    const u16* __restrict__ W1g = (const u16*)(ws + WS_W1P);
    __syncthreads();
    if (t < 180) {
        int y = t / 15, xx = t % 15;
        u16 tap[9], msk[9];
        int nv = 0;
        #pragma unroll
        for (int ky = 0; ky < 3; ++ky) {
            #pragma unroll
            for (int kx = 0; kx < 3; ++kx) {
                int yy = y + ky - 1, xc = xx + kx - 1;
                bool v = (yy >= 0 && yy < 12 && xc >= 0 && xc < 15);
                int yl = min(max(yy, 0), 11), xl = min(max(xc, 0), 14);
                tap[ky*3+kx] = As[yl*15 + xl];
                msk[ky*3+kx] = v ? (u16)0xFFFF : (u16)0;
                nv += v ? 12 : 0;
            }
        }
        for (int oc = 0; oc < 48; ++oc) {
            int acc = 0;
            #pragma unroll
            for (int k = 0; k < 9; ++k)
                acc += __popc((unsigned)((u16)(tap[k] ^ W1g[oc*9 + k]) & msk[k]));
            cmap[oc*180 + t] = (signed char)(nv - 2*acc);
        }
    }
    __syncthreads();
    signed char* gp = (signed char*)(ws + WS_P1) + (size_t)b*7392;
    for (int i = t; i < 7392; i += 192) {
        int c = i / 154, s = i % 154, py = s / 14, px = s % 14;
        int base = c*180 + py*15 + px;
        int mx = max(max((int)cmap[base],    (int)cmap[base+1]),
                     max((int)cmap[base+15], (int)cmap[base+16]));
        pl[i] = (signed char)mx;
        gp[i] = (signed char)mx;
    }
    __syncthreads();
    int wv = t >> 6, ln = t & 63, slot = b & 7;
    u64* st = (u64*)(ws + WS_STATS);
    for (int c = wv; c < 48; c += 3) {
        int sum = 0, sq = 0;
        for (int s = ln; s < 154; s += 64) {
            int v = pl[c*154 + s];
            sum += v; sq += v*v;
        }
        #pragma unroll
        for (int off = 32; off >= 1; off >>= 1) {
            sum += __shfl_down(sum, off);
            sq  += __shfl_down(sq, off);
        }
        if (ln == 0) {
            atomicAdd(&st[c*8 + slot],        (u64)(long long)sum);
            atomicAdd(&st[(48 + c)*8 + slot], (u64)(long long)sq);
        }
    }
}

// ---- BN1 apply -> xb2 + A2 masks + conv2 (taps-in-regs) + BN2 stats ----
__global__ __launch_bounds__(128)
void kA_bn1conv2(const float* __restrict__ g1, const float* __restrict__ b1,
                 float* __restrict__ dout, char* __restrict__ ws) {
    __shared__ float sc[48], sh[48];
    __shared__ int sm_i[1848];     // pooled1 s8 [48][154]
    __shared__ u64 As[154];
    __shared__ short c2s[5184];    // [48][108]
    signed char* sm = (signed char*)sm_i;
    int t = threadIdx.x, b = blockIdx.x;
    const int* gp = (const int*)(ws + WS_P1 + (size_t)b*7392);
    for (int i4 = t; i4 < 1848; i4 += 128) sm_i[i4] = gp[i4];
    const u64* __restrict__ W2g = (const u64*)(ws + WS_W2P);
    if (t < 48) {
        const long long* st = (const long long*)(ws + WS_STATS);
        long long s = 0, q = 0;
        #pragma unroll
        for (int k = 0; k < 8; ++k) { s += st[t*8 + k]; q += st[(48 + t)*8 + k]; }
        double N = 630784.0;   // 4096*11*14
        double mean = (double)s / N;
        double var  = (double)q / N - mean*mean;
        double scale = (double)g1[t] / sqrt(var + 1e-5);
        sc[t] = (float)scale;
        sh[t] = (float)((double)b1[t] - mean*scale);
    }
    __syncthreads();
    float4* xo = (float4*)(dout + XB2_OFF + (size_t)b*7392);
    for (int i4 = t; i4 < 1848; i4 += 128) {
        int pv = sm_i[i4];
        int i = i4*4;
        float4 o;
        int c0 = i/154, c1 = (i+1)/154, c2i = (i+2)/154, c3 = (i+3)/154;
        o.x = fsign(sc[c0]*(float)(signed char)(pv)        + sh[c0]);
        o.y = fsign(sc[c1]*(float)(signed char)(pv >> 8)   + sh[c1]);
        o.z = fsign(sc[c2i]*(float)(signed char)(pv >> 16) + sh[c2i]);
        o.w = fsign(sc[c3]*(float)(signed char)(pv >> 24)  + sh[c3]);
        xo[i4] = o;
    }
    u64* A2g = (u64*)(ws + WS_A1) + (size_t)b*154;
    for (int s = t; s < 154; s += 128) {
        u64 m = 0;
        #pragma unroll
        for (int c = 0; c < 48; ++c)
            if (sc[c]*(float)sm[c*154 + s] + sh[c] > 0.0f) m |= (1ull << c);
        As[s] = m;
        A2g[s] = m;
    }
    __syncthreads();
    if (t < 108) {
        int oy = t / 12, ox = t % 12;
        u64 tap[9];
        #pragma unroll
        for (int ky = 0; ky < 3; ++ky)
            #pragma unroll
            for (int kx = 0; kx < 3; ++kx)
                tap[ky*3+kx] = As[(oy+ky)*14 + ox + kx];
        for (int oc = 0; oc < 48; ++oc) {
            int acc = 0;
            #pragma unroll
            for (int k = 0; k < 9; ++k)
                acc += __popcll(tap[k] ^ W2g[oc*9 + k]);
            c2s[oc*108 + t] = (short)(432 - 2*acc);
        }
    }
    __syncthreads();
    int wv = t >> 6, ln = t & 63, slot = b & 7;
    u64* st = (u64*)(ws + WS_STATS);
    for (int c = wv; c < 48; c += 2) {
        int sum = 0, sq = 0;
        for (int s = ln; s < 108; s += 64) {
            int v = c2s[c*108 + s];
            sum += v; sq += v*v;
        }
        #pragma unroll
        for (int off = 32; off >= 1; off >>= 1) {
            sum += __shfl_down(sum, off);
            sq  += __shfl_down(sq, off);
        }
        if (ln == 0) {
            atomicAdd(&st[(96 + c)*8 + slot],  (u64)(long long)sum);
            atomicAdd(&st[(144 + c)*8 + slot], (u64)(long long)sq);
        }
    }
}

// ---- conv2 recompute + BN2 apply -> xb3 + conv3 + pool + BN3 stats ----
__global__ __launch_bounds__(128)
void kB_bn2conv3(const float* __restrict__ g2, const float* __restrict__ b2,
                 float* __restrict__ dout, char* __restrict__ ws) {
    __shared__ float sc[48], sh[48];
    __shared__ u64 As[154];
    __shared__ short c2s[5184];    // [48][108]
    __shared__ u64 A3[108];
    __shared__ short cm[3360];     // [48][70]
    __shared__ short pls[2592];    // [48][54]
    int t = threadIdx.x, b = blockIdx.x;
    const u64* A2g = (const u64*)(ws + WS_A1) + (size_t)b*154;
    for (int s = t; s < 154; s += 128) As[s] = A2g[s];
    const u64* __restrict__ W2g = (const u64*)(ws + WS_W2P);
    const u64* __restrict__ W3g = (const u64*)(ws + WS_W3P);
    if (t < 48) {
        const long long* st = (const long long*)(ws + WS_STATS);
        long long s = 0, q = 0;
        #pragma unroll
        for (int k = 0; k < 8; ++k) { s += st[(96 + t)*8 + k]; q += st[(144 + t)*8 + k]; }
        double N = 442368.0;   // 4096*9*12
        double mean = (double)s / N;
        double var  = (double)q / N - mean*mean;
        double scale = (double)g2[t] / sqrt(var + 1e-5);
        sc[t] = (float)scale;
        sh[t] = (float)((double)b2[t] - mean*scale);
    }
    __syncthreads();
    if (t < 108) {
        int oy = t / 12, ox = t % 12;
        u64 tap[9];
        #pragma unroll
        for (int ky = 0; ky < 3; ++ky)
            #pragma unroll
            for (int kx = 0; kx < 3; ++kx)
                tap[ky*3+kx] = As[(oy+ky)*14 + ox + kx];
        for (int oc = 0; oc < 48; ++oc) {
            int acc = 0;
            #pragma unroll
            for (int k = 0; k < 9; ++k)
                acc += __popcll(tap[k] ^ W2g[oc*9 + k]);
            c2s[oc*108 + t] = (short)(432 - 2*acc);
        }
    }
    __syncthreads();
    float4* xo = (float4*)(dout + XB3_OFF + (size_t)b*5184);
    for (int i4 = t; i4 < 1296; i4 += 128) {   // 108/4=27 per channel
        int c = i4 / 27, s4 = i4 % 27;
        short4 v4 = *(const short4*)&c2s[c*108 + s4*4];
        float4 o;
        o.x = fsign(sc[c]*(float)v4.x + sh[c]);
        o.y = fsign(sc[c]*(float)v4.y + sh[c]);
        o.z = fsign(sc[c]*(float)v4.z + sh[c]);
        o.w = fsign(sc[c]*(float)v4.w + sh[c]);
        xo[i4] = o;
    }
    if (t < 108) {
        u64 m = 0;
        #pragma unroll
        for (int c = 0; c < 48; ++c)
            if (sc[c]*(float)c2s[c*108 + t] + sh[c] > 0.0f) m |= (1ull << c);
        A3[t] = m;
    }
    __syncthreads();
    if (t < 70) {
        int oy = t / 10, ox = t % 10;
        u64 tap[9];
        #pragma unroll
        for (int ky = 0; ky < 3; ++ky)
            #pragma unroll
            for (int kx = 0; kx < 3; ++kx)
                tap[ky*3+kx] = A3[(oy+ky)*12 + ox + kx];
        for (int oc = 0; oc < 48; ++oc) {
            int acc = 0;
            #pragma unroll
            for (int k = 0; k < 9; ++k)
                acc += __popcll(tap[k] ^ W3g[oc*9 + k]);
            cm[oc*70 + t] = (short)(432 - 2*acc);
        }
    }
    __syncthreads();
    short* p3g = (short*)(ws + WS_P1) + (size_t)b*2592;
    for (int i = t; i < 2592; i += 128) {
        int c = i / 54, s = i % 54, py = s / 9, px = s % 9;
        int base = c*70 + py*10 + px;
        int mx = max(max((int)cm[base],    (int)cm[base+1]),
                     max((int)cm[base+10], (int)cm[base+11]));
        pls[i] = (short)mx;
        p3g[i] = (short)mx;
    }
    __syncthreads();
    int wv = t >> 6, ln = t & 63, slot = b & 7;
    u64* st = (u64*)(ws + WS_STATS);
    for (int c = wv; c < 48; c += 2) {
        int sum = 0, sq = 0;
        if (ln < 54) {
            int v = pls[c*54 + ln];
            sum = v; sq = v*v;
        }
        #pragma unroll
        for (int off = 32; off >= 1; off >>= 1) {
            sum += __shfl_down(sum, off);
            sq  += __shfl_down(sq, off);
        }
        if (ln == 0) {
            atomicAdd(&st[(192 + c)*8 + slot], (u64)(long long)sum);
            atomicAdd(&st[(240 + c)*8 + slot], (u64)(long long)sq);
        }
    }
}

// ---- BN3 apply -> fb + FC ----
__global__ __launch_bounds__(256)
void kC_fbfc(const float* __restrict__ g3, const float* __restrict__ b3,
             float* __restrict__ dout, char* __restrict__ ws) {
    __shared__ float sc[48], sh[48];
    __shared__ short4 sm4[648];
    __shared__ unsigned char nib[648];
    __shared__ u64 fbb[41];
    short* sm = (short*)sm4;
    int t = threadIdx.x, b = blockIdx.x;
    const short4* p3 = (const short4*)((const short*)(ws + WS_P1) + (size_t)b*2592);
    for (int i4 = t; i4 < 648; i4 += 256) sm4[i4] = p3[i4];
    if (t < 48) {
        const long long* st = (const long long*)(ws + WS_STATS);
        long long s = 0, q = 0;
        #pragma unroll
        for (int k = 0; k < 8; ++k) { s += st[(192 + t)*8 + k]; q += st[(240 + t)*8 + k]; }
        double N = 221184.0;   // 4096*6*9
        double mean = (double)s / N;
        double var  = (double)q / N - mean*mean;
        double scale = (double)g3[t] / sqrt(var + 1e-5);
        sc[t] = (float)scale;
        sh[t] = (float)((double)b3[t] - mean*scale);
    }
    __syncthreads();
    float4* fo = (float4*)(dout + FB_OFF + (size_t)b*2592);
    for (int i4 = t; i4 < 648; i4 += 256) {
        int i = i4*4;
        float4 o;
        unsigned n = 0;
        int c0 = i/54, c1 = (i+1)/54, c2 = (i+2)/54, c3 = (i+3)/54;
        float v0 = sc[c0]*(float)sm[i]   + sh[c0];
        float v1 = sc[c1]*(float)sm[i+1] + sh[c1];
        float v2 = sc[c2]*(float)sm[i+2] + sh[c2];
        float v3 = sc[c3]*(float)sm[i+3] + sh[c3];
        o.x = fsign(v0); o.y = fsign(v1); o.z = fsign(v2); o.w = fsign(v3);
        if (v0 > 0.0f) n |= 1u;
        if (v1 > 0.0f) n |= 2u;
        if (v2 > 0.0f) n |= 4u;
        if (v3 > 0.0f) n |= 8u;
        fo[i4] = o;
        nib[i4] = (unsigned char)n;
    }
    __syncthreads();
    if (t < 41) {
        u64 m = 0;
        #pragma unroll
        for (int k = 0; k < 16; ++k) {
            int j = t*16 + k;
            if (j < 648) m |= ((u64)nib[j]) << (4*k);
        }
        fbb[t] = m;
    }
    __syncthreads();
    if (t < 5) {
        const u64* Wf = (const u64*)(ws + WS_WFCP) + t*41;
        int acc = 0;
        #pragma unroll
        for (int j = 0; j < 41; ++j) acc += __popcll(fbb[j] ^ Wf[j]);
        dout[OUT_OFF + b*5 + t] = (float)(2592 - 2*acc);
    }
}

extern "C" void kernel_launch(void* const* d_in, const int* in_sizes, int n_in,
                              void* d_out, int out_size, void* d_ws, size_t ws_size,
                              hipStream_t stream) {
    const float* x   = (const float*)d_in[0];
    const float* w1  = (const float*)d_in[1];
    const float* g1  = (const float*)d_in[2];
    const float* b1  = (const float*)d_in[3];
    const float* w2  = (const float*)d_in[4];
    const float* g2  = (const float*)d_in[5];
    const float* b2  = (const float*)d_in[6];
    const float* w3  = (const float*)d_in[7];
    const float* g3  = (const float*)d_in[8];
    const float* b3  = (const float*)d_in[9];
    const float* wfc = (const float*)d_in[10];
    float* out = (float*)d_out;
    char* ws = (char*)d_ws;

    hipLaunchKernelGGL(kw_pack,     dim3(1),    dim3(512), 0, stream, w1, w2, w3, wfc, ws);
    hipLaunchKernelGGL(k0_binx,     dim3(720),  dim3(256), 0, stream, x, out, ws);
    hipLaunchKernelGGL(k1_conv1,    dim3(NB),   dim3(192), 0, stream, ws);
    hipLaunchKernelGGL(kA_bn1conv2, dim3(NB),   dim3(128), 0, stream, g1, b1, out, ws);
    hipLaunchKernelGGL(kB_bn2conv3, dim3(NB),   dim3(128), 0, stream, g2, b2, out, ws);
    hipLaunchKernelGGL(kC_fbfc,     dim3(NB),   dim3(256), 0, stream, g3, b3, out, ws);
}

// Round 4
// 720.248 us; speedup vs baseline: 1.0670x; 1.0670x over previous
//
#include <hip/hip_runtime.h>
#include <stdint.h>

typedef unsigned long long u64;
typedef unsigned short u16;

#define NB 4096

// ---------------- workspace layout (bytes) ----------------
// stats: long long, idx = stat*8 + slot; stat: c, 48+c (x3 stages at +96)
#define WS_STATS 0          // 2304*8 = 18432
#define WS_CONST 18432      // float[288]: sc1,sh1,sc2,sh2,sc3,sh3
#define WS_W1P   20480      // u16[432]
#define WS_W2P   24576      // u64[432]
#define WS_W3P   28672      // u64[432]
#define WS_WFCP  32768      // u64[205]
#define WS_A1    40960      // u16[4096*180]; reused as A2 u64[4096*154]
#define WS_P1    5111808    // pooled1 s8[4096*7392]; reused as pooled3 s16[4096*2592]

// ---------------- d_out offsets (floats) ----------------
#define OUT_OFF 0
#define XB1_OFF 20480
#define XB2_OFF 8867840
#define XB3_OFF 39145472
#define FB_OFF  60379136

__device__ __forceinline__ float fsign(float v) {
    return (v > 0.0f) ? 1.0f : ((v < 0.0f) ? -1.0f : 0.0f);
}

// ---- weight binarize+pack, stats zero ----
__global__ __launch_bounds__(512)
void kw_pack(const float* __restrict__ w1, const float* __restrict__ w2,
             const float* __restrict__ w3, const float* __restrict__ wfc,
             u16* __restrict__ W1P, u64* __restrict__ W2P, u64* __restrict__ W3P,
             u64* __restrict__ WFCP, long long* __restrict__ stats) {
    int t = threadIdx.x;
    for (int i = t; i < 2304; i += 512) stats[i] = 0;
    if (t < 432) {
        int oc = t / 9, p = t % 9;
        u16 m1 = 0;
        for (int c = 0; c < 12; ++c)
            if (w1[oc*108 + c*9 + p] > 0.0f) m1 |= (u16)(1u << c);
        W1P[t] = m1;
        u64 m2 = 0, m3 = 0;
        for (int c = 0; c < 48; ++c) {
            if (w2[oc*432 + c*9 + p] > 0.0f) m2 |= (1ull << c);
            if (w3[oc*432 + c*9 + p] > 0.0f) m3 |= (1ull << c);
        }
        W2P[t] = m2;
        W3P[t] = m3;
    }
    if (t < 205) {
        int o = t / 41, j = t % 41;
        u64 m = 0;
        for (int l = 0; l < 64; ++l) {
            int k = j*64 + l;
            if (k < 2592 && wfc[o*2592 + k] > 0.0f) m |= (1ull << l);
        }
        WFCP[t] = m;
    }
}

// ---- BN consts: sc = g/sqrt(var+eps), sh = b - mean*sc ----
__global__ __launch_bounds__(64)
void kbn(const float* __restrict__ g, const float* __restrict__ bb,
         const long long* __restrict__ st, float* __restrict__ cst, float Nf) {
    int t = threadIdx.x;
    if (t < 48) {
        long long s = 0, q = 0;
        #pragma unroll
        for (int k = 0; k < 8; ++k) { s += st[t*8 + k]; q += st[(48 + t)*8 + k]; }
        double N = (double)Nf;
        double mean = (double)s / N;
        double var  = (double)q / N - mean*mean;
        double scale = (double)g[t] / sqrt(var + 1e-5);
        cst[t]      = (float)scale;
        cst[48 + t] = (float)((double)bb[t] - mean*scale);
    }
}

// ---- binarize x -> xb1 floats (float4) + A1 bitmasks ----
__global__ __launch_bounds__(256)
void k0_binx(const float* __restrict__ x, float* __restrict__ dout,
             u16* __restrict__ A1) {
    int id = blockIdx.x*256 + threadIdx.x;   // 184320 = 4096*45
    int b = id / 45, s4 = id % 45;
    const float4* xp = (const float4*)(x + b*2160);
    float4* op = (float4*)(dout + XB1_OFF + (size_t)b*2160);
    u16 m0 = 0, m1 = 0, m2 = 0, m3 = 0;
    #pragma unroll
    for (int c = 0; c < 12; ++c) {
        float4 v = xp[c*45 + s4];
        float4 o;
        o.x = fsign(v.x); o.y = fsign(v.y); o.z = fsign(v.z); o.w = fsign(v.w);
        op[c*45 + s4] = o;
        u16 bit = (u16)(1u << c);
        if (v.x > 0.0f) m0 |= bit;
        if (v.y > 0.0f) m1 |= bit;
        if (v.z > 0.0f) m2 |= bit;
        if (v.w > 0.0f) m3 |= bit;
    }
    ushort4 mm; mm.x = m0; mm.y = m1; mm.z = m2; mm.w = m3;
    *((ushort4*)(A1 + b*180 + s4*4)) = mm;
}

// ---- conv1 (pad1) + pool + stats1 ----
__global__ __launch_bounds__(192)
void k1_conv1(const u16* __restrict__ W1, const u16* __restrict__ A1,
              int* __restrict__ P1, u64* __restrict__ stats) {
    __shared__ u16 As[180];
    __shared__ int cmap_i[2160];   // s8 [48][180]
    __shared__ int pl_i[1848];     // s8 [48][154]
    signed char* cmap = (signed char*)cmap_i;
    signed char* pl = (signed char*)pl_i;
    int t = threadIdx.x, b = blockIdx.x;
    if (t < 180) As[t] = A1[b*180 + t];
    __syncthreads();
    if (t < 180) {
        int y = t / 15, xx = t % 15;
        u16 tap[9], msk[9];
        int nv = 0;
        #pragma unroll
        for (int ky = 0; ky < 3; ++ky) {
            #pragma unroll
            for (int kx = 0; kx < 3; ++kx) {
                int yy = y + ky - 1, xc = xx + kx - 1;
                bool v = (yy >= 0 && yy < 12 && xc >= 0 && xc < 15);
                int yl = min(max(yy, 0), 11), xl = min(max(xc, 0), 14);
                tap[ky*3+kx] = As[yl*15 + xl];
                msk[ky*3+kx] = v ? (u16)0xFFFF : (u16)0;
                nv += v ? 12 : 0;
            }
        }
        #pragma unroll 4
        for (int oc = 0; oc < 48; ++oc) {
            int acc = 0;
            #pragma unroll
            for (int k = 0; k < 9; ++k)
                acc += __popc((unsigned)((u16)(tap[k] ^ W1[oc*9 + k]) & msk[k]));
            cmap[oc*180 + t] = (signed char)(nv - 2*acc);
        }
    }
    __syncthreads();
    int* gp = P1 + (size_t)b*1848;
    for (int i4 = t; i4 < 1848; i4 += 192) {
        int r = 0;
        #pragma unroll
        for (int u = 0; u < 4; ++u) {
            int i = i4*4 + u;
            int c = i / 154, s = i % 154, py = s / 14, px = s % 14;
            int base = c*180 + py*15 + px;
            int mx = max(max((int)cmap[base],    (int)cmap[base+1]),
                         max((int)cmap[base+15], (int)cmap[base+16]));
            r |= (mx & 0xff) << (8*u);
        }
        pl_i[i4] = r;
        gp[i4] = r;
    }
    __syncthreads();
    int wv = t >> 6, ln = t & 63, slot = b & 7;
    for (int c = wv; c < 48; c += 3) {
        int sum = 0, sq = 0;
        for (int s = ln; s < 154; s += 64) {
            int v = pl[c*154 + s];
            sum += v; sq += v*v;
        }
        #pragma unroll
        for (int off = 32; off >= 1; off >>= 1) {
            sum += __shfl_down(sum, off);
            sq  += __shfl_down(sq, off);
        }
        if (ln == 0) {
            atomicAdd((u64*)&stats[c*8 + slot],        (u64)(long long)sum);
            atomicAdd((u64*)&stats[(48 + c)*8 + slot], (u64)(long long)sq);
        }
    }
}

// ---- BN1 apply -> xb2 + A2 + conv2 + stats2 ----
__global__ __launch_bounds__(256)
void kA_bn1conv2(const float* __restrict__ cst, const int4* __restrict__ P1,
                 float* __restrict__ dout, u64* __restrict__ A2,
                 const u64* __restrict__ W2, u64* __restrict__ stats) {
    __shared__ float sc[48], sh[48];
    __shared__ int sm_i[1848];     // s8 [48][154]
    __shared__ u64 As[154];
    __shared__ short c2s[5184];    // [48][108]
    signed char* sm = (signed char*)sm_i;
    int t = threadIdx.x, b = blockIdx.x;
    const int4* gp = P1 + (size_t)b*462;
    for (int i = t; i < 462; i += 256) ((int4*)sm_i)[i] = gp[i];
    if (t < 48) sc[t] = cst[t];
    else if (t < 96) sh[t - 48] = cst[t];
    __syncthreads();
    float4* xo = (float4*)(dout + XB2_OFF + (size_t)b*7392);
    for (int i4 = t; i4 < 1848; i4 += 256) {
        int pv = sm_i[i4];
        int i = i4*4;
        float4 o;
        int c0 = i/154, c1 = (i+1)/154, c2i = (i+2)/154, c3 = (i+3)/154;
        o.x = fsign(sc[c0]*(float)(signed char)(pv)        + sh[c0]);
        o.y = fsign(sc[c1]*(float)(signed char)(pv >> 8)   + sh[c1]);
        o.z = fsign(sc[c2i]*(float)(signed char)(pv >> 16) + sh[c2i]);
        o.w = fsign(sc[c3]*(float)(signed char)(pv >> 24)  + sh[c3]);
        xo[i4] = o;
    }
    if (t < 154) {
        u64 m = 0;
        #pragma unroll
        for (int c = 0; c < 48; ++c)
            if (sc[c]*(float)sm[c*154 + t] + sh[c] > 0.0f) m |= (1ull << c);
        As[t] = m;
        A2[(size_t)b*154 + t] = m;
    }
    __syncthreads();
    if (t < 216) {
        int pos = (t < 108) ? t : (t - 108);
        int ocb = (t < 108) ? 0 : 24;
        int oy = pos / 12, ox = pos % 12;
        u64 tap[9];
        #pragma unroll
        for (int ky = 0; ky < 3; ++ky)
            #pragma unroll
            for (int kx = 0; kx < 3; ++kx)
                tap[ky*3+kx] = As[(oy+ky)*14 + ox + kx];
        #pragma unroll 4
        for (int oc = ocb; oc < ocb + 24; ++oc) {
            int acc = 0;
            #pragma unroll
            for (int k = 0; k < 9; ++k)
                acc += __popcll(tap[k] ^ W2[oc*9 + k]);
            c2s[oc*108 + pos] = (short)(432 - 2*acc);
        }
    }
    __syncthreads();
    int wv = t >> 6, ln = t & 63, slot = b & 7;
    for (int c = wv; c < 48; c += 4) {
        int sum = 0, sq = 0;
        for (int s = ln; s < 108; s += 64) {
            int v = c2s[c*108 + s];
            sum += v; sq += v*v;
        }
        #pragma unroll
        for (int off = 32; off >= 1; off >>= 1) {
            sum += __shfl_down(sum, off);
            sq  += __shfl_down(sq, off);
        }
        if (ln == 0) {
            atomicAdd((u64*)&stats[(96 + c)*8 + slot],  (u64)(long long)sum);
            atomicAdd((u64*)&stats[(144 + c)*8 + slot], (u64)(long long)sq);
        }
    }
}

// ---- conv2 recompute + BN2 apply -> xb3 + conv3 + pool + stats3 ----
__global__ __launch_bounds__(256)
void kB_bn2conv3(const float* __restrict__ cst, const u64* __restrict__ A2,
                 const u64* __restrict__ W2, const u64* __restrict__ W3,
                 float* __restrict__ dout, short* __restrict__ P3,
                 u64* __restrict__ stats) {
    __shared__ float sc[48], sh[48];
    __shared__ u64 As[154];
    __shared__ short c2s[5184];    // [48][108]
    __shared__ u64 A3[108];
    __shared__ short cm[3360];     // [48][70]
    __shared__ short pls[2592];    // [48][54]
    int t = threadIdx.x, b = blockIdx.x;
    if (t < 154) As[t] = A2[(size_t)b*154 + t];
    if (t < 48) sc[t] = cst[t];
    else if (t < 96) sh[t - 48] = cst[t];
    __syncthreads();
    if (t < 216) {
        int pos = (t < 108) ? t : (t - 108);
        int ocb = (t < 108) ? 0 : 24;
        int oy = pos / 12, ox = pos % 12;
        u64 tap[9];
        #pragma unroll
        for (int ky = 0; ky < 3; ++ky)
            #pragma unroll
            for (int kx = 0; kx < 3; ++kx)
                tap[ky*3+kx] = As[(oy+ky)*14 + ox + kx];
        #pragma unroll 4
        for (int oc = ocb; oc < ocb + 24; ++oc) {
            int acc = 0;
            #pragma unroll
            for (int k = 0; k < 9; ++k)
                acc += __popcll(tap[k] ^ W2[oc*9 + k]);
            c2s[oc*108 + pos] = (short)(432 - 2*acc);
        }
    }
    __syncthreads();
    float4* xo = (float4*)(dout + XB3_OFF + (size_t)b*5184);
    for (int i4 = t; i4 < 1296; i4 += 256) {   // 27 short4 per channel
        int c = i4 / 27, s4 = i4 % 27;
        short4 v4 = *(const short4*)&c2s[c*108 + s4*4];
        float4 o;
        o.x = fsign(sc[c]*(float)v4.x + sh[c]);
        o.y = fsign(sc[c]*(float)v4.y + sh[c]);
        o.z = fsign(sc[c]*(float)v4.z + sh[c]);
        o.w = fsign(sc[c]*(float)v4.w + sh[c]);
        xo[i4] = o;
    }
    if (t < 108) {
        u64 m = 0;
        #pragma unroll
        for (int c = 0; c < 48; ++c)
            if (sc[c]*(float)c2s[c*108 + t] + sh[c] > 0.0f) m |= (1ull << c);
        A3[t] = m;
    }
    __syncthreads();
    if (t < 210) {
        int grp = (t < 70) ? 0 : ((t < 140) ? 1 : 2);
        int pos = t - grp*70;
        int ocb = grp*16;
        int oy = pos / 10, ox = pos % 10;
        u64 tap[9];
        #pragma unroll
        for (int ky = 0; ky < 3; ++ky)
            #pragma unroll
            for (int kx = 0; kx < 3; ++kx)
                tap[ky*3+kx] = A3[(oy+ky)*12 + ox + kx];
        #pragma unroll 4
        for (int oc = ocb; oc < ocb + 16; ++oc) {
            int acc = 0;
            #pragma unroll
            for (int k = 0; k < 9; ++k)
                acc += __popcll(tap[k] ^ W3[oc*9 + k]);
            cm[oc*70 + pos] = (short)(432 - 2*acc);
        }
    }
    __syncthreads();
    int* p3g = (int*)(P3 + (size_t)b*2592);
    for (int i2 = t; i2 < 1296; i2 += 256) {   // 2 pooled vals per thread
        int i = i2*2;
        int c = i / 54, s = i % 54, py = s / 9, px = s % 9;
        int base = c*70 + py*10 + px;
        int m0 = max(max((int)cm[base],    (int)cm[base+1]),
                     max((int)cm[base+10], (int)cm[base+11]));
        int m1 = max(max((int)cm[base+1],  (int)cm[base+2]),
                     max((int)cm[base+11], (int)cm[base+12]));
        // note: (i+1) stays in same channel row (54 even), px+1 case handled:
        if (px == 8) {  // second elem starts new pooled row py+1, px=0
            int base2 = c*70 + (py+1)*10;
            m1 = max(max((int)cm[base2],    (int)cm[base2+1]),
                     max((int)cm[base2+10], (int)cm[base2+11]));
        }
        pls[i] = (short)m0;
        pls[i+1] = (short)m1;
        p3g[i2] = (m0 & 0xffff) | (m1 << 16);
    }
    __syncthreads();
    int wv = t >> 6, ln = t & 63, slot = b & 7;
    for (int c = wv; c < 48; c += 4) {
        int sum = 0, sq = 0;
        if (ln < 54) {
            int v = pls[c*54 + ln];
            sum = v; sq = v*v;
        }
        #pragma unroll
        for (int off = 32; off >= 1; off >>= 1) {
            sum += __shfl_down(sum, off);
            sq  += __shfl_down(sq, off);
        }
        if (ln == 0) {
            atomicAdd((u64*)&stats[(192 + c)*8 + slot], (u64)(long long)sum);
            atomicAdd((u64*)&stats[(240 + c)*8 + slot], (u64)(long long)sq);
        }
    }
}

// ---- BN3 apply -> fb + FC ----
__global__ __launch_bounds__(256)
void kC_fbfc(const float* __restrict__ cst, const short* __restrict__ P3,
             const u64* __restrict__ WFC, float* __restrict__ dout) {
    __shared__ float sc[48], sh[48];
    __shared__ short4 sm4[648];
    __shared__ unsigned char nib[648];
    __shared__ u64 fbb[41];
    short* sm = (short*)sm4;
    int t = threadIdx.x, b = blockIdx.x;
    const short4* p3 = (const short4*)(P3 + (size_t)b*2592);
    for (int i4 = t; i4 < 648; i4 += 256) sm4[i4] = p3[i4];
    if (t < 48) sc[t] = cst[t];
    else if (t < 96) sh[t - 48] = cst[t];
    __syncthreads();
    float4* fo = (float4*)(dout + FB_OFF + (size_t)b*2592);
    for (int i4 = t; i4 < 648; i4 += 256) {
        int i = i4*4;
        float4 o;
        unsigned n = 0;
        int c0 = i/54, c1 = (i+1)/54, c2 = (i+2)/54, c3 = (i+3)/54;
        float v0 = sc[c0]*(float)sm[i]   + sh[c0];
        float v1 = sc[c1]*(float)sm[i+1] + sh[c1];
        float v2 = sc[c2]*(float)sm[i+2] + sh[c2];
        float v3 = sc[c3]*(float)sm[i+3] + sh[c3];
        o.x = fsign(v0); o.y = fsign(v1); o.z = fsign(v2); o.w = fsign(v3);
        if (v0 > 0.0f) n |= 1u;
        if (v1 > 0.0f) n |= 2u;
        if (v2 > 0.0f) n |= 4u;
        if (v3 > 0.0f) n |= 8u;
        fo[i4] = o;
        nib[i4] = (unsigned char)n;
    }
    __syncthreads();
    if (t < 41) {
        u64 m = 0;
        #pragma unroll
        for (int k = 0; k < 16; ++k) {
            int j = t*16 + k;
            if (j < 648) m |= ((u64)nib[j]) << (4*k);
        }
        fbb[t] = m;
    }
    __syncthreads();
    if (t < 5) {
        const u64* Wf = WFC + t*41;
        int acc = 0;
        #pragma unroll
        for (int j = 0; j < 41; ++j) acc += __popcll(fbb[j] ^ Wf[j]);
        dout[OUT_OFF + b*5 + t] = (float)(2592 - 2*acc);
    }
}

extern "C" void kernel_launch(void* const* d_in, const int* in_sizes, int n_in,
                              void* d_out, int out_size, void* d_ws, size_t ws_size,
                              hipStream_t stream) {
    const float* x   = (const float*)d_in[0];
    const float* w1  = (const float*)d_in[1];
    const float* g1  = (const float*)d_in[2];
    const float* b1  = (const float*)d_in[3];
    const float* w2  = (const float*)d_in[4];
    const float* g2  = (const float*)d_in[5];
    const float* b2  = (const float*)d_in[6];
    const float* w3  = (const float*)d_in[7];
    const float* g3  = (const float*)d_in[8];
    const float* b3  = (const float*)d_in[9];
    const float* wfc = (const float*)d_in[10];
    float* out = (float*)d_out;
    char* ws = (char*)d_ws;

    long long* stats = (long long*)(ws + WS_STATS);
    float*     cst   = (float*)(ws + WS_CONST);
    u16*       W1P   = (u16*)(ws + WS_W1P);
    u64*       W2P   = (u64*)(ws + WS_W2P);
    u64*       W3P   = (u64*)(ws + WS_W3P);
    u64*       WFCP  = (u64*)(ws + WS_WFCP);
    u16*       A1    = (u16*)(ws + WS_A1);
    u64*       A2    = (u64*)(ws + WS_A1);
    int*       P1    = (int*)(ws + WS_P1);
    short*     P3    = (short*)(ws + WS_P1);

    hipLaunchKernelGGL(kw_pack,     dim3(1),    dim3(512), 0, stream,
                       w1, w2, w3, wfc, W1P, W2P, W3P, WFCP, stats);
    hipLaunchKernelGGL(k0_binx,     dim3(720),  dim3(256), 0, stream, x, out, A1);
    hipLaunchKernelGGL(k1_conv1,    dim3(NB),   dim3(192), 0, stream,
                       W1P, A1, P1, (u64*)stats);
    hipLaunchKernelGGL(kbn,         dim3(1),    dim3(64),  0, stream,
                       g1, b1, stats, cst, 630784.0f);
    hipLaunchKernelGGL(kA_bn1conv2, dim3(NB),   dim3(256), 0, stream,
                       cst, (const int4*)P1, out, A2, W2P, (u64*)stats);
    hipLaunchKernelGGL(kbn,         dim3(1),    dim3(64),  0, stream,
                       g2, b2, stats + 96*8, cst + 96, 442368.0f);
    hipLaunchKernelGGL(kB_bn2conv3, dim3(NB),   dim3(256), 0, stream,
                       cst + 96, A2, W2P, W3P, out, P3, (u64*)stats);
    hipLaunchKernelGGL(kbn,         dim3(1),    dim3(64),  0, stream,
                       g3, b3, stats + 192*8, cst + 192, 221184.0f);
    hipLaunchKernelGGL(kC_fbfc,     dim3(NB),   dim3(256), 0, stream,
                       cst + 192, P3, WFCP, out);
}

// Round 5
// 618.376 us; speedup vs baseline: 1.2428x; 1.1647x over previous
//
#include <hip/hip_runtime.h>
#include <stdint.h>

typedef unsigned long long u64;
typedef unsigned int u32;
typedef unsigned short u16;
typedef unsigned char u8;
typedef signed char s8;

#define NB 4096

// ---------------- workspace layout (bytes) ----------------
#define WS_STATS 0          // long long[288*8]: (stat*8+slot); stages at +96*8
#define WS_W1Q   20480      // u32[240]  (conv1 weights packed 2-taps-per-u32)
#define WS_W2P   24576      // u64[432]
#define WS_W3P   28672      // u64[432]
#define WS_WFCP  32768      // u64[205]
#define WS_A2    40960      // u64[4096*154] = 5,046,272
#define WS_P1    5087232    // pooled1 u8[4096*8448] padded [48][11][16]; reused as P3 short[4096][48][60]

// ---------------- d_out offsets (floats) ----------------
#define OUT_OFF 0
#define XB1_OFF 20480
#define XB2_OFF 8867840
#define XB3_OFF 39145472
#define FB_OFF  60379136

__device__ __forceinline__ float fsign(float v) {
    return (v > 0.0f) ? 1.0f : ((v < 0.0f) ? -1.0f : 0.0f);
}
__device__ __forceinline__ int sb8(int v, int k) {   // signed byte k of int
    return (int)(s8)(v >> (8*k));
}
__device__ __forceinline__ int sh16(int v, int h) {  // signed short h of int
    return h ? (v >> 16) : (int)(short)v;
}

// ---- weight binarize+pack, stats zero ----
__global__ __launch_bounds__(512)
void kw_pack(const float* __restrict__ w1, const float* __restrict__ w2,
             const float* __restrict__ w3, const float* __restrict__ wfc,
             u32* __restrict__ W1Q, u64* __restrict__ W2P, u64* __restrict__ W3P,
             u64* __restrict__ WFCP, long long* __restrict__ stats) {
    int t = threadIdx.x;
    for (int i = t; i < 2304; i += 512) stats[i] = 0;
    if (t < 48) {
        u16 m1[9];
        #pragma unroll
        for (int p = 0; p < 9; ++p) {
            u16 m = 0;
            for (int c = 0; c < 12; ++c)
                if (w1[t*108 + c*9 + p] > 0.0f) m |= (u16)(1u << c);
            m1[p] = m;
        }
        #pragma unroll
        for (int j = 0; j < 4; ++j)
            W1Q[t*5 + j] = (u32)m1[2*j] | ((u32)m1[2*j+1] << 16);
        W1Q[t*5 + 4] = (u32)m1[8];
    }
    if (t < 432) {
        int oc = t / 9, p = t % 9;
        u64 m2 = 0, m3 = 0;
        for (int c = 0; c < 48; ++c) {
            if (w2[oc*432 + c*9 + p] > 0.0f) m2 |= (1ull << c);
            if (w3[oc*432 + c*9 + p] > 0.0f) m3 |= (1ull << c);
        }
        W2P[t] = m2;
        W3P[t] = m3;
    }
    if (t < 205) {
        int o = t / 41, j = t % 41;
        u64 m = 0;
        for (int l = 0; l < 64; ++l) {
            int k = j*64 + l;
            if (k < 2592 && wfc[o*2592 + k] > 0.0f) m |= (1ull << l);
        }
        WFCP[t] = m;
    }
}

// ---- binarize x -> xb1, conv1 (pad1), pool -> P1 (padded), stats1 ----
__global__ __launch_bounds__(192)
void k1(const float* __restrict__ x, const u32* __restrict__ W1Q,
        float* __restrict__ dout, u8* __restrict__ P1g, u64* __restrict__ stats) {
    __shared__ u16 As[180];
    __shared__ int cmap[2304];   // s8 [48][12][16]
    __shared__ int2 part[192];
    int t = threadIdx.x, b = blockIdx.x;
    // phase0: binarize x -> xb1 + masks
    if (t < 180) {
        const float* xp = x + b*2160 + t;
        float* xo = dout + XB1_OFF + (size_t)b*2160 + t;
        u16 m = 0;
        #pragma unroll
        for (int c = 0; c < 12; ++c) {
            float v = xp[c*180];
            xo[c*180] = fsign(v);
            if (v > 0.0f) m |= (u16)(1u << c);
        }
        As[t] = m;
    }
    __syncthreads();
    // phase1: conv1, packed popc
    if (t < 180) {
        int y = t / 15, xx = t % 15;
        u16 tap[9], msk[9];
        int nv = 0;
        #pragma unroll
        for (int ky = 0; ky < 3; ++ky) {
            #pragma unroll
            for (int kx = 0; kx < 3; ++kx) {
                int yy = y + ky - 1, xc = xx + kx - 1;
                bool v = (yy >= 0 && yy < 12 && xc >= 0 && xc < 15);
                int yl = min(max(yy, 0), 11), xl = min(max(xc, 0), 14);
                tap[ky*3+kx] = As[yl*15 + xl];
                msk[ky*3+kx] = v ? (u16)0xFFFF : (u16)0;
                nv += v ? 12 : 0;
            }
        }
        u32 tq[5], mq[5];
        #pragma unroll
        for (int j = 0; j < 4; ++j) {
            tq[j] = (u32)tap[2*j] | ((u32)tap[2*j+1] << 16);
            mq[j] = (u32)msk[2*j] | ((u32)msk[2*j+1] << 16);
        }
        tq[4] = tap[8]; mq[4] = msk[8];
        s8* cb = (s8*)cmap;
        #pragma unroll 4
        for (int oc = 0; oc < 48; ++oc) {
            int acc = 0;
            #pragma unroll
            for (int j = 0; j < 5; ++j)
                acc += __popc((tq[j] ^ W1Q[oc*5 + j]) & mq[j]);
            cb[oc*192 + y*16 + xx] = (s8)(nv - 2*acc);
        }
    }
    __syncthreads();
    // phase2: pool 2x2/s1 + stats, per-thread channel ownership
    {
        int c = t >> 2, q = t & 3;
        int r0 = 3*q, nr = (q < 3) ? 3 : 2;
        int rowv[4][4];
        #pragma unroll
        for (int j = 0; j < 4; ++j)
            if (j <= nr) {
                #pragma unroll
                for (int i = 0; i < 4; ++i)
                    rowv[j][i] = cmap[c*48 + (r0 + j)*4 + i];
            }
        int sum = 0, sq = 0;
        u8* gp = P1g + (size_t)b*8448 + c*176;
        #pragma unroll
        for (int pr = 0; pr < 3; ++pr) {
            if (pr < nr) {
                int o0 = 0, o1 = 0, o2 = 0, o3 = 0;
                #pragma unroll
                for (int k = 0; k < 14; ++k) {
                    int a0 = sb8(rowv[pr][k>>2], k&3);
                    int a1 = sb8(rowv[pr][(k+1)>>2], (k+1)&3);
                    int b0 = sb8(rowv[pr+1][k>>2], k&3);
                    int b1 = sb8(rowv[pr+1][(k+1)>>2], (k+1)&3);
                    int mx = max(max(a0, a1), max(b0, b1));
                    sum += mx; sq += mx*mx;
                    int sh = 8*(k&3);
                    if ((k>>2) == 0) o0 |= (mx & 255) << sh;
                    else if ((k>>2) == 1) o1 |= (mx & 255) << sh;
                    else if ((k>>2) == 2) o2 |= (mx & 255) << sh;
                    else o3 |= (mx & 255) << sh;
                }
                *((int4*)(gp + (r0 + pr)*16)) = make_int4(o0, o1, o2, o3);
            }
        }
        part[t] = make_int2(sum, sq);
    }
    __syncthreads();
    if (t < 48) {
        int s = 0, q = 0;
        #pragma unroll
        for (int k = 0; k < 4; ++k) { s += part[t*4+k].x; q += part[t*4+k].y; }
        int slot = b & 7;
        atomicAdd(&stats[t*8 + slot],        (u64)(long long)s);
        atomicAdd(&stats[(48 + t)*8 + slot], (u64)(long long)q);
    }
}

// ---- BN1 consts + apply -> xb2 + A2 + conv2 + stats2 ----
__global__ __launch_bounds__(256)
void kA(const float* __restrict__ g1, const float* __restrict__ b1,
        const long long* __restrict__ statsIn, const int4* __restrict__ P1g4,
        float* __restrict__ dout, u64* __restrict__ A2,
        const u64* __restrict__ W2, u64* __restrict__ statsOut) {
    __shared__ float sc[48], sh[48];
    __shared__ int smP[2112];      // padded pooled1 bytes [48][176]
    __shared__ u64 As[154];
    __shared__ short c2s[5184];    // [48][108]
    __shared__ int2 part[192];
    int t = threadIdx.x, b = blockIdx.x;
    for (int i = t; i < 528; i += 256) ((int4*)smP)[i] = P1g4[(size_t)b*528 + i];
    if (t < 48) {
        long long s = 0, q = 0;
        #pragma unroll
        for (int k = 0; k < 8; ++k) { s += statsIn[t*8 + k]; q += statsIn[(48 + t)*8 + k]; }
        double N = 630784.0;   // 4096*11*14
        double mean = (double)s / N;
        double var  = (double)q / N - mean*mean;
        double scale = (double)g1[t] / sqrt(var + 1e-5);
        sc[t] = (float)scale;
        sh[t] = (float)((double)b1[t] - mean*scale);
    }
    __syncthreads();
    const s8* smb = (const s8*)smP;
    float4* xo = (float4*)(dout + XB2_OFF + (size_t)b*7392);
    for (int i4 = t; i4 < 462; i4 += 256) {
        int i = 4*i4;
        float r[4];
        #pragma unroll
        for (int k = 0; k < 4; ++k) {
            int idx = i + k;
            int c = idx / 154, s = idx - 154*c;
            int row = s / 14, px = s - 14*row;
            int v = smb[c*176 + row*16 + px];
            r[k] = fsign(sc[c]*(float)v + sh[c]);
        }
        float4 o; o.x = r[0]; o.y = r[1]; o.z = r[2]; o.w = r[3];
        xo[i4] = o;
    }
    if (t < 154) {
        int row = t / 14, px = t - 14*row;
        int po = row*16 + px;
        u64 m = 0;
        #pragma unroll
        for (int c = 0; c < 48; ++c)
            if (sc[c]*(float)smb[c*176 + po] + sh[c] > 0.0f) m |= (1ull << c);
        As[t] = m;
        A2[(size_t)b*154 + t] = m;
    }
    __syncthreads();
    if (t < 216) {
        int pos = (t < 108) ? t : (t - 108);
        int ocb = (t < 108) ? 0 : 24;
        int oy = pos / 12, ox = pos - 12*oy;
        u64 tap[9];
        #pragma unroll
        for (int ky = 0; ky < 3; ++ky)
            #pragma unroll
            for (int kx = 0; kx < 3; ++kx)
                tap[ky*3+kx] = As[(oy+ky)*14 + ox + kx];
        #pragma unroll 4
        for (int oc = ocb; oc < ocb + 24; ++oc) {
            int acc = 0;
            #pragma unroll
            for (int k = 0; k < 9; ++k)
                acc += __popcll(tap[k] ^ W2[oc*9 + k]);
            c2s[oc*108 + pos] = (short)(432 - 2*acc);
        }
    }
    __syncthreads();
    if (t < 192) {
        int c = t >> 2, q = t & 3;
        const int* ci = (const int*)(c2s + c*108);
        int sum = 0, sq = 0;
        for (int j = q; j < 54; j += 4) {
            int v2 = ci[j];
            int lo = (int)(short)v2, hi = v2 >> 16;
            sum += lo + hi; sq += lo*lo + hi*hi;
        }
        part[t] = make_int2(sum, sq);
    }
    __syncthreads();
    if (t < 48) {
        int s = 0, q = 0;
        #pragma unroll
        for (int k = 0; k < 4; ++k) { s += part[t*4+k].x; q += part[t*4+k].y; }
        int slot = b & 7;
        atomicAdd(&statsOut[(96 + t)*8 + slot],  (u64)(long long)s);
        atomicAdd(&statsOut[(144 + t)*8 + slot], (u64)(long long)q);
    }
}

// ---- conv2 recompute + BN2 apply -> xb3 + conv3 + pool -> P3 + stats3 ----
__global__ __launch_bounds__(256)
void kB(const float* __restrict__ g2, const float* __restrict__ b2,
        const long long* __restrict__ statsIn, const u64* __restrict__ A2,
        const u64* __restrict__ W2, const u64* __restrict__ W3,
        float* __restrict__ dout, int* __restrict__ P3i,
        u64* __restrict__ statsOut) {
    __shared__ float sc[48], sh[48];
    __shared__ u64 As[154];
    __shared__ short c2s[5184];    // [48][108]
    __shared__ u64 A3[108];
    __shared__ short cm[3360];     // [48][70]
    __shared__ int2 part[192];
    int t = threadIdx.x, b = blockIdx.x;
    if (t < 154) As[t] = A2[(size_t)b*154 + t];
    if (t < 48) {
        long long s = 0, q = 0;
        #pragma unroll
        for (int k = 0; k < 8; ++k) { s += statsIn[(96 + t)*8 + k]; q += statsIn[(144 + t)*8 + k]; }
        double N = 442368.0;   // 4096*9*12
        double mean = (double)s / N;
        double var  = (double)q / N - mean*mean;
        double scale = (double)g2[t] / sqrt(var + 1e-5);
        sc[t] = (float)scale;
        sh[t] = (float)((double)b2[t] - mean*scale);
    }
    __syncthreads();
    if (t < 216) {
        int pos = (t < 108) ? t : (t - 108);
        int ocb = (t < 108) ? 0 : 24;
        int oy = pos / 12, ox = pos - 12*oy;
        u64 tap[9];
        #pragma unroll
        for (int ky = 0; ky < 3; ++ky)
            #pragma unroll
            for (int kx = 0; kx < 3; ++kx)
                tap[ky*3+kx] = As[(oy+ky)*14 + ox + kx];
        #pragma unroll 4
        for (int oc = ocb; oc < ocb + 24; ++oc) {
            int acc = 0;
            #pragma unroll
            for (int k = 0; k < 9; ++k)
                acc += __popcll(tap[k] ^ W2[oc*9 + k]);
            c2s[oc*108 + pos] = (short)(432 - 2*acc);
        }
    }
    __syncthreads();
    float4* xo = (float4*)(dout + XB3_OFF + (size_t)b*5184);
    for (int i4 = t; i4 < 1296; i4 += 256) {
        int c = i4 / 27, s4 = i4 - 27*c;
        short4 v4 = *(const short4*)&c2s[c*108 + s4*4];
        float4 o;
        o.x = fsign(sc[c]*(float)v4.x + sh[c]);
        o.y = fsign(sc[c]*(float)v4.y + sh[c]);
        o.z = fsign(sc[c]*(float)v4.z + sh[c]);
        o.w = fsign(sc[c]*(float)v4.w + sh[c]);
        xo[i4] = o;
    }
    if (t < 108) {
        u64 m = 0;
        #pragma unroll
        for (int c = 0; c < 48; ++c)
            if (sc[c]*(float)c2s[c*108 + t] + sh[c] > 0.0f) m |= (1ull << c);
        A3[t] = m;
    }
    __syncthreads();
    if (t < 210) {
        int grp = (t < 70) ? 0 : ((t < 140) ? 1 : 2);
        int pos = t - grp*70;
        int ocb = grp*16;
        int oy = pos / 10, ox = pos - 10*oy;
        u64 tap[9];
        #pragma unroll
        for (int ky = 0; ky < 3; ++ky)
            #pragma unroll
            for (int kx = 0; kx < 3; ++kx)
                tap[ky*3+kx] = A3[(oy+ky)*12 + ox + kx];
        #pragma unroll 4
        for (int oc = ocb; oc < ocb + 16; ++oc) {
            int acc = 0;
            #pragma unroll
            for (int k = 0; k < 9; ++k)
                acc += __popcll(tap[k] ^ W3[oc*9 + k]);
            cm[oc*70 + pos] = (short)(432 - 2*acc);
        }
    }
    __syncthreads();
    // pool 2x2/s1 on [7][10] -> [6][9] + stats, per-thread channel ownership
    {
        int c = t >> 2, q = t & 3;
        if (t < 192) {
            int pr0 = (q < 2) ? 2*q : (q + 2);      // rows: {0,1},{2,3},{4},{5}
            int npr = (q < 2) ? 2 : 1;
            int rowv[3][5];
            const int* cmi = (const int*)(cm + c*70);
            #pragma unroll
            for (int j = 0; j < 3; ++j)
                if (j <= npr) {
                    #pragma unroll
                    for (int i = 0; i < 5; ++i)
                        rowv[j][i] = cmi[(pr0 + j)*5 + i];
                }
            int sum = 0, sq = 0;
            int* gp = P3i + (size_t)b*1440 + c*30;
            #pragma unroll
            for (int pr = 0; pr < 2; ++pr) {
                if (pr < npr) {
                    int o[5] = {0, 0, 0, 0, 0};
                    #pragma unroll
                    for (int k = 0; k < 9; ++k) {
                        int a0 = sh16(rowv[pr][k>>1], k&1);
                        int a1 = sh16(rowv[pr][(k+1)>>1], (k+1)&1);
                        int b0 = sh16(rowv[pr+1][k>>1], k&1);
                        int b1 = sh16(rowv[pr+1][(k+1)>>1], (k+1)&1);
                        int mx = max(max(a0, a1), max(b0, b1));
                        sum += mx; sq += mx*mx;
                        o[k>>1] |= (mx & 0xffff) << (16*(k&1));
                    }
                    #pragma unroll
                    for (int j = 0; j < 5; ++j) gp[(pr0 + pr)*5 + j] = o[j];
                }
            }
            part[t] = make_int2(sum, sq);
        }
    }
    __syncthreads();
    if (t < 48) {
        int s = 0, q = 0;
        #pragma unroll
        for (int k = 0; k < 4; ++k) { s += part[t*4+k].x; q += part[t*4+k].y; }
        int slot = b & 7;
        atomicAdd(&statsOut[(192 + t)*8 + slot], (u64)(long long)s);
        atomicAdd(&statsOut[(240 + t)*8 + slot], (u64)(long long)q);
    }
}

// ---- BN3 consts + apply -> fb + FC ----
__global__ __launch_bounds__(256)
void kC(const float* __restrict__ g3, const float* __restrict__ b3,
        const long long* __restrict__ statsIn, const int4* __restrict__ P3g4,
        const u64* __restrict__ WFC, float* __restrict__ dout) {
    __shared__ float sc[48], sh[48];
    __shared__ int smP[1440];      // padded pooled3 shorts [48][60]
    __shared__ u8 nib[648];
    __shared__ u64 fbb[41];
    int t = threadIdx.x, b = blockIdx.x;
    for (int i = t; i < 360; i += 256) ((int4*)smP)[i] = P3g4[(size_t)b*360 + i];
    if (t < 48) {
        long long s = 0, q = 0;
        #pragma unroll
        for (int k = 0; k < 8; ++k) { s += statsIn[(192 + t)*8 + k]; q += statsIn[(240 + t)*8 + k]; }
        double N = 221184.0;   // 4096*6*9
        double mean = (double)s / N;
        double var  = (double)q / N - mean*mean;
        double scale = (double)g3[t] / sqrt(var + 1e-5);
        sc[t] = (float)scale;
        sh[t] = (float)((double)b3[t] - mean*scale);
    }
    __syncthreads();
    const short* smS = (const short*)smP;
    float4* fo = (float4*)(dout + FB_OFF + (size_t)b*2592);
    for (int i4 = t; i4 < 648; i4 += 256) {
        int i = 4*i4;
        float r[4];
        unsigned n = 0;
        #pragma unroll
        for (int k = 0; k < 4; ++k) {
            int idx = i + k;
            int c = idx / 54, s = idx - 54*c;
            int row = s / 9, px = s - 9*row;
            float bn = sc[c]*(float)smS[c*60 + row*10 + px] + sh[c];
            r[k] = fsign(bn);
            if (bn > 0.0f) n |= (1u << k);
        }
        float4 o; o.x = r[0]; o.y = r[1]; o.z = r[2]; o.w = r[3];
        fo[i4] = o;
        nib[i4] = (u8)n;
    }
    __syncthreads();
    if (t < 41) {
        u64 m = 0;
        #pragma unroll
        for (int k = 0; k < 16; ++k) {
            int j = t*16 + k;
            if (j < 648) m |= ((u64)nib[j]) << (4*k);
        }
        fbb[t] = m;
    }
    __syncthreads();
    if (t < 5) {
        const u64* Wf = WFC + t*41;
        int acc = 0;
        #pragma unroll
        for (int j = 0; j < 41; ++j) acc += __popcll(fbb[j] ^ Wf[j]);
        dout[OUT_OFF + b*5 + t] = (float)(2592 - 2*acc);
    }
}

extern "C" void kernel_launch(void* const* d_in, const int* in_sizes, int n_in,
                              void* d_out, int out_size, void* d_ws, size_t ws_size,
                              hipStream_t stream) {
    const float* x   = (const float*)d_in[0];
    const float* w1  = (const float*)d_in[1];
    const float* g1  = (const float*)d_in[2];
    const float* b1  = (const float*)d_in[3];
    const float* w2  = (const float*)d_in[4];
    const float* g2  = (const float*)d_in[5];
    const float* b2  = (const float*)d_in[6];
    const float* w3  = (const float*)d_in[7];
    const float* g3  = (const float*)d_in[8];
    const float* b3  = (const float*)d_in[9];
    const float* wfc = (const float*)d_in[10];
    float* out = (float*)d_out;
    char* ws = (char*)d_ws;

    long long* stats = (long long*)(ws + WS_STATS);
    u32*       W1Q   = (u32*)(ws + WS_W1Q);
    u64*       W2P   = (u64*)(ws + WS_W2P);
    u64*       W3P   = (u64*)(ws + WS_W3P);
    u64*       WFCP  = (u64*)(ws + WS_WFCP);
    u64*       A2    = (u64*)(ws + WS_A2);
    u8*        P1g   = (u8*)(ws + WS_P1);
    int*       P3i   = (int*)(ws + WS_P1);

    hipLaunchKernelGGL(kw_pack, dim3(1),  dim3(512), 0, stream,
                       w1, w2, w3, wfc, W1Q, W2P, W3P, WFCP, stats);
    hipLaunchKernelGGL(k1,      dim3(NB), dim3(192), 0, stream,
                       x, W1Q, out, P1g, (u64*)stats);
    hipLaunchKernelGGL(kA,      dim3(NB), dim3(256), 0, stream,
                       g1, b1, stats, (const int4*)P1g, out, A2, W2P, (u64*)stats);
    hipLaunchKernelGGL(kB,      dim3(NB), dim3(256), 0, stream,
                       g2, b2, stats, A2, W2P, W3P, out, P3i, (u64*)stats);
    hipLaunchKernelGGL(kC,      dim3(NB), dim3(256), 0, stream,
                       g3, b3, stats, (const int4*)P3i, WFCP, out);
}